// Round 18
// baseline (269.426 us; speedup 1.0000x reference)
//
#include <hip/hip_runtime.h>
#include <math.h>

#define AOFF 2097152   // recon = 32*64*1024 floats, alphas follow
#define LOFF 2359296   // AOFF + 32*8*1024

typedef __attribute__((ext_vector_type(8))) short short8;
typedef __attribute__((ext_vector_type(4))) float f32x4;

__device__ __forceinline__ int clsf(int v) { return v < 2 ? v : (v > 29 ? v - 27 : 2); }

__device__ __forceinline__ unsigned int f2bfu(float x) {
    unsigned int u = __float_as_uint(x);
    return (u + 0x7FFFu + ((u >> 16) & 1u)) >> 16;
}
__device__ __forceinline__ unsigned int cvt2(float a, float b) {
    return f2bfu(a) | (f2bfu(b) << 16);
}
__device__ __forceinline__ float bf2f(unsigned short u) {
    return __uint_as_float(((unsigned int)u) << 16);
}

// ---------------- tapabc: per-tap dot with affine pos coeffs (w1 staged in LDS) ----------------
__global__ void tapabc_kernel(const float* __restrict__ pw, const float* __restrict__ pb,
                              const float* __restrict__ w1, float* __restrict__ tapabc) {
    __shared__ float A3[384];
    __shared__ float wl[8192];
    int tap = blockIdx.x, t = threadIdx.x;     // 192 threads
    if (t < 128) {
        float p0 = pw[t * 4], p1 = pw[t * 4 + 1], p2 = pw[t * 4 + 2], p3 = pw[t * 4 + 3];
        A3[t] = p2 + p3 + pb[t];
        A3[128 + t] = p0 - p2;
        A3[256 + t] = p1 - p3;
    }
    for (int e = t; e < 8192; e += 192) wl[e] = w1[e * 25 + tap];
    __syncthreads();
    int o = t & 63, comp = t >> 6;
    const float* a = A3 + comp * 128;
    float s = 0.f;
    for (int i = 0; i < 128; ++i) s = fmaf(wl[i * 64 + o], a[i], s);
    tapabc[(tap * 64 + o) * 3 + comp] = s;
}

// ---------------- P fill: channel-PAIR interleaved float2 layout ----------------
__global__ void pfill_kernel(const float* __restrict__ tapabc, const float* __restrict__ b1,
                             float* __restrict__ P2) {
    __shared__ float uv[75];
    int o = blockIdx.x, t = threadIdx.x;       // 1024 threads
    if (t < 75) {
        int cls = t / 3, comp = t % 3;
        int cy = cls / 5, cx = cls % 5;
        const int klo[5] = {2, 1, 0, 0, 0}, khi[5] = {4, 4, 4, 3, 2};
        const float inv31 = 1.f / 31.f;
        float s = (comp == 0) ? b1[o] : 0.f;
        for (int ky = klo[cy]; ky <= khi[cy]; ++ky)
            for (int kx = klo[cx]; kx <= khi[cx]; ++kx) {
                int tap = (4 - ky) * 5 + (4 - kx);
                const float* tp = &tapabc[(tap * 64 + o) * 3];
                if (comp == 0) s += tp[0] + tp[1] * (ky - 2) * inv31 + tp[2] * (kx - 2) * inv31;
                else if (comp == 1) s += tp[1] * inv31;
                else s += tp[2] * inv31;
            }
        uv[t] = s;
    }
    __syncthreads();
    int y = t >> 5, x = t & 31;
    int cls = clsf(y) * 5 + clsf(x);
    float val = uv[cls * 3] + uv[cls * 3 + 1] * y + uv[cls * 3 + 2] * x;
    P2[((o >> 1) << 11) + (t << 1) + (o & 1)] = val;
}

// ---------------- merged: Wsum (gid < 204800) + weight prep (rest) ----------------
__global__ void prep_ws_kernel(const float* __restrict__ w1,
                               const float* __restrict__ a1w, const float* __restrict__ c1w,
                               const float* __restrict__ c2w, const float* __restrict__ ct2w,
                               float* __restrict__ Wsum, short* __restrict__ wtall) {
    int gid = blockIdx.x * 256 + threadIdx.x;
    const int klo[5] = {2, 1, 0, 0, 0}, khi[5] = {4, 4, 4, 3, 2};
    if (gid < 204800) {
        int idx = gid;
        int cls = idx >> 13;
        int i = (idx >> 6) & 127;
        int o = idx & 63;
        int cy = cls / 5, cx = cls % 5;
        float s = 0.f;
        for (int ky = klo[cy]; ky <= khi[cy]; ++ky)
            for (int kx = klo[cx]; kx <= khi[cx]; ++kx)
                s += w1[(i * 64 + o) * 25 + (4 - ky) * 5 + (4 - kx)];
        Wsum[idx] = s;
        return;
    }
    gid -= 204800;
    if (gid < 36864) {                                  // a1 / c1 : I=32,O=64
        const float* src = gid < 18432 ? a1w : c1w;
        int idx = gid < 18432 ? gid : gid - 18432;
        int j = idx & 7, fi = idx >> 3;
        int o = fi % 64, g = (fi / 64) & 3, t = fi / 256;
        int i = g * 8 + j;
        wtall[gid] = (short)f2bfu(src[(o * 32 + i) * 9 + (t / 3) * 3 + (t % 3)]);
    } else if (gid < 73728) {                           // c2 : I=64,O=64
        int idx = gid - 36864;
        int j = idx & 7, fi = idx >> 3;
        int o = fi % 64, g = (fi / 64) & 3, ks = (fi / 256) & 1, t = fi / 512;
        int i = ks * 32 + g * 8 + j;
        wtall[gid] = (short)f2bfu(c2w[(o * 64 + i) * 9 + (t / 3) * 3 + (t % 3)]);
    } else if (gid < 124928) {                          // convT2 : flipped 5x5
        int idx = gid - 73728;
        int j = idx & 7, fi = idx >> 3;
        int o = fi & 31, g = (fi >> 5) & 3, ks = (fi >> 7) & 1, t = fi >> 8;
        int i = ks * 32 + g * 8 + j;
        int ky = t / 5, kx = t % 5;
        wtall[gid] = (short)f2bfu(ct2w[((i * 32 + o) * 5 + (4 - ky)) * 5 + (4 - kx)]);
    }
}

// ---------------- M[n][cls][o] ----------------
__global__ void m_kernel(const float* __restrict__ latent, const float* __restrict__ Wsum,
                         float* __restrict__ M) {
    int n = blockIdx.x, cls = blockIdx.y, o = threadIdx.x;
    const float* l = &latent[n * 128];
    const float* w = &Wsum[cls * 8192 + o];
    float a0 = 0.f, a1 = 0.f;
    for (int i = 0; i < 128; i += 2) {
        a0 = fmaf(l[i], w[i * 64], a0);
        a1 = fmaf(l[i + 1], w[(i + 1) * 64], a1);
    }
    M[(n * 25 + cls) * 64 + o] = a0 + a1;
}

// ---------------- conv5 (convT2): 4-row tiles, split-K, padded LDS ----------------
__global__ __launch_bounds__(256) void conv5_kernel(
        const float* __restrict__ M, const float* __restrict__ P2,
        const short* __restrict__ wt, const float* __restrict__ b2,
        unsigned short* __restrict__ featb) {
    __shared__ __align__(16) short tile[8 * 36 * 40];   // 23040 B
    __shared__ float Ml[1600];                          // 6400 B
    const int n = blockIdx.x, y0 = blockIdx.y * 4;
    const int tid = threadIdx.x, w = tid >> 6, l = tid & 63;
    const int lx = l & 15, lg = l >> 4;

    for (int e = tid; e < 1600; e += 256) Ml[e] = M[n * 1600 + e];
    __syncthreads();

    f32x4 acc[2][2];   // [m][colf], 1 output row per wave
    #pragma unroll
    for (int m = 0; m < 2; ++m)
        #pragma unroll
        for (int c = 0; c < 2; ++c) acc[m][c] = (f32x4){0.f, 0.f, 0.f, 0.f};

    #pragma unroll 1
    for (int ks = 0; ks < 2; ++ks) {
        if (ks) __syncthreads();
        // stage 8 rows x 36 cols x 16 channel-pairs = 4608 packs (18/thread)
        #pragma unroll
        for (int it = 0; it < 18; ++it) {
            int e = tid + it * 256;
            int cx = e % 36;
            int q = e / 36;
            int ipl = q & 15;
            int r = q >> 4;
            int gy = y0 - 2 + r, gx = cx - 2;
            unsigned int pack = 0u;
            if (gy >= 0 && gy < 32 && gx >= 0 && gx < 32) {
                int cls = clsf(gy) * 5 + clsf(gx);
                int pp = gy * 32 + gx;
                float2 pv = ((const float2*)P2)[((ks * 16 + ipl) << 10) + pp];
                float2 ml = ((const float2*)Ml)[cls * 32 + ks * 16 + ipl];
                pack = cvt2(fmaxf(ml.x + pv.x, 0.f), fmaxf(ml.y + pv.y, 0.f));
            }
            *(unsigned int*)((char*)tile + (r * 36 + cx) * 80 + ipl * 4) = pack;
        }
        __syncthreads();
        for (int kx = 0; kx < 5; ++kx) {
            short8 af[5][2];
            #pragma unroll
            for (int ky = 0; ky < 5; ++ky)
                #pragma unroll
                for (int m = 0; m < 2; ++m)
                    af[ky][m] = *(const short8*)(wt + (ky * 5 + kx) * 2048 +
                                                 ((ks * 4 + lg) * 32 + m * 16 + lx) * 8);
            #pragma unroll
            for (int colf = 0; colf < 2; ++colf) {
                const int cbase = ((w) * 36 + kx + colf * 16 + lx) * 80 + lg * 16;
                short8 bc[5];
                #pragma unroll
                for (int ir = 0; ir < 5; ++ir)
                    bc[ir] = *(const short8*)((char*)tile + cbase + ir * (36 * 80));
                #pragma unroll
                for (int ky = 0; ky < 5; ++ky)
                    #pragma unroll
                    for (int m = 0; m < 2; ++m)
                        acc[m][colf] = __builtin_amdgcn_mfma_f32_16x16x32_bf16(
                            af[ky][m], bc[ky], acc[m][colf], 0, 0, 0);
            }
        }
    }

    #pragma unroll
    for (int m = 0; m < 2; ++m)
        #pragma unroll
        for (int colf = 0; colf < 2; ++colf) {
            int x = colf * 16 + lx;
            unsigned long long pk = 0ull;
            #pragma unroll
            for (int r = 0; r < 4; ++r) {
                int och = m * 16 + lg * 4 + r;
                float v = fmaxf(acc[m][colf][r] + b2[och], 0.f);
                pk |= (unsigned long long)f2bfu(v) << (16 * r);
            }
            *(unsigned long long*)(featb + (n * 1024 + (y0 + w) * 32 + x) * 32
                                   + m * 16 + lg * 4) = pk;
        }
}

// ---------------- conv3 (I=32): 4-row tiles, 1 row/wave (c1 path) ----------------
template<int ACT>
__global__ __launch_bounds__(256, 6) void conv3_kernel(
        const unsigned short* __restrict__ in_, const short* __restrict__ wt,
        const float* __restrict__ bias, unsigned short* __restrict__ out_) {
    __shared__ __align__(16) short smem[6 * 34 * 40];   // 16320 B
    const int n = blockIdx.x, y0 = blockIdx.y * 4;
    const int tid = threadIdx.x, w = tid >> 6, l = tid & 63;
    const int lx = l & 15, lg = l >> 4;

    for (int e = tid; e < 816; e += 256) {
        int px = e >> 2, qc = e & 3;
        int r = px / 34, cx = px - r * 34;
        int gy = y0 - 1 + r, gx = cx - 1;
        short8 v8 = (short8){0, 0, 0, 0, 0, 0, 0, 0};
        if (gy >= 0 && gy < 32 && gx >= 0 && gx < 32)
            v8 = *(const short8*)(in_ + (n * 1024 + gy * 32 + gx) * 32 + qc * 8);
        *(short8*)((char*)smem + px * 80 + qc * 16) = v8;
    }
    __syncthreads();

    f32x4 acc[4][2];
    #pragma unroll
    for (int m = 0; m < 4; ++m)
        #pragma unroll
        for (int c = 0; c < 2; ++c) acc[m][c] = (f32x4){0.f, 0.f, 0.f, 0.f};

    #pragma unroll
    for (int kx = 0; kx < 3; ++kx) {
        short8 bc[2][3];
        #pragma unroll
        for (int colf = 0; colf < 2; ++colf) {
            const int cbase = (w * 34 + kx + colf * 16 + lx) * 80 + lg * 16;
            #pragma unroll
            for (int ir = 0; ir < 3; ++ir)
                bc[colf][ir] = *(const short8*)((char*)smem + cbase + ir * (34 * 80));
        }
        #pragma unroll
        for (int m = 0; m < 4; ++m) {
            short8 af[3];
            #pragma unroll
            for (int ky = 0; ky < 3; ++ky)
                af[ky] = *(const short8*)(wt + (ky * 3 + kx) * 2048 +
                                          (lg * 64 + m * 16 + lx) * 8);
            #pragma unroll
            for (int ky = 0; ky < 3; ++ky)
                #pragma unroll
                for (int colf = 0; colf < 2; ++colf)
                    acc[m][colf] = __builtin_amdgcn_mfma_f32_16x16x32_bf16(
                        af[ky], bc[colf][ky], acc[m][colf], 0, 0, 0);
        }
    }

    #pragma unroll
    for (int m = 0; m < 4; ++m)
        #pragma unroll
        for (int colf = 0; colf < 2; ++colf) {
            int x = colf * 16 + lx;
            unsigned long long pk = 0ull;
            #pragma unroll
            for (int r = 0; r < 4; ++r) {
                int och = m * 16 + lg * 4 + r;
                float v = acc[m][colf][r] + bias[och];
                if (ACT == 1) v = v / (1.f + expf(-v));
                pk |= (unsigned long long)f2bfu(v) << (16 * r);
            }
            *(unsigned long long*)(out_ + (n * 1024 + (y0 + w) * 32 + x) * 64
                                   + m * 16 + lg * 4) = pk;
        }
}

// ---------------- conv3a2: a1 conv + a2 projection via MFMA ----------------
__global__ __launch_bounds__(256, 6) void conv3a2_kernel(
        const unsigned short* __restrict__ in_, const short* __restrict__ wt,
        const float* __restrict__ bias, const float* __restrict__ a2w,
        float* __restrict__ s9) {
    __shared__ __align__(16) short smem[8192];   // 16384 B: staging / repack
    __shared__ float wl9[576];
    const int n = blockIdx.x, y0 = blockIdx.y * 4;
    const int tid = threadIdx.x, w = tid >> 6, l = tid & 63;
    const int lx = l & 15, lg = l >> 4;

    for (int e = tid; e < 576; e += 256) wl9[e] = a2w[e];
    for (int e = tid; e < 816; e += 256) {
        int px = e >> 2, qc = e & 3;
        int r = px / 34, cx = px - r * 34;
        int gy = y0 - 1 + r, gx = cx - 1;
        short8 v8 = (short8){0, 0, 0, 0, 0, 0, 0, 0};
        if (gy >= 0 && gy < 32 && gx >= 0 && gx < 32)
            v8 = *(const short8*)(in_ + (n * 1024 + gy * 32 + gx) * 32 + qc * 8);
        *(short8*)((char*)smem + px * 80 + qc * 16) = v8;
    }
    __syncthreads();

    f32x4 acc[4][2];
    #pragma unroll
    for (int m = 0; m < 4; ++m)
        #pragma unroll
        for (int c = 0; c < 2; ++c) acc[m][c] = (f32x4){0.f, 0.f, 0.f, 0.f};

    #pragma unroll
    for (int kx = 0; kx < 3; ++kx) {
        short8 bc[2][3];
        #pragma unroll
        for (int colf = 0; colf < 2; ++colf) {
            const int cbase = (w * 34 + kx + colf * 16 + lx) * 80 + lg * 16;
            #pragma unroll
            for (int ir = 0; ir < 3; ++ir)
                bc[colf][ir] = *(const short8*)((char*)smem + cbase + ir * (34 * 80));
        }
        #pragma unroll
        for (int m = 0; m < 4; ++m) {
            short8 af[3];
            #pragma unroll
            for (int ky = 0; ky < 3; ++ky)
                af[ky] = *(const short8*)(wt + (ky * 3 + kx) * 2048 +
                                          (lg * 64 + m * 16 + lx) * 8);
            #pragma unroll
            for (int ky = 0; ky < 3; ++ky)
                #pragma unroll
                for (int colf = 0; colf < 2; ++colf)
                    acc[m][colf] = __builtin_amdgcn_mfma_f32_16x16x32_bf16(
                        af[ky], bc[colf][ky], acc[m][colf], 0, 0, 0);
        }
    }

    short8 af9[2];
    #pragma unroll
    for (int ks = 0; ks < 2; ++ks)
        #pragma unroll
        for (int j = 0; j < 8; ++j) {
            int ch = ks * 32 + lg * 8 + j;
            float v = (lx < 9) ? wl9[ch * 9 + lx] : 0.f;
            af9[ks][j] = (short)f2bfu(v);
        }

    __syncthreads();
    char* base = (char*)smem + w * 4096;
    #pragma unroll
    for (int m = 0; m < 4; ++m)
        #pragma unroll
        for (int colf = 0; colf < 2; ++colf) {
            int px = colf * 16 + lx;
            unsigned long long pk = 0ull;
            #pragma unroll
            for (int r = 0; r < 4; ++r) {
                int och = m * 16 + lg * 4 + r;
                float v = acc[m][colf][r] + bias[och];
                v = v / (1.f + expf(-v));
                pk |= (unsigned long long)f2bfu(v) << (16 * r);
            }
            int slot = 2 * m + (lg >> 1);
            int off = px * 128 + (((slot ^ (px & 7)) << 4)) + (lg & 1) * 8;
            *(unsigned long long*)(base + off) = pk;
        }
    __syncthreads();

    #pragma unroll
    for (int colf = 0; colf < 2; ++colf) {
        int px = colf * 16 + lx;
        f32x4 sp = (f32x4){0.f, 0.f, 0.f, 0.f};
        #pragma unroll
        for (int ks = 0; ks < 2; ++ks) {
            int slot = ks * 4 + lg;
            short8 bf = *(const short8*)(base + px * 128 + ((slot ^ (px & 7)) << 4));
            sp = __builtin_amdgcn_mfma_f32_16x16x32_bf16(af9[ks], bf, sp, 0, 0, 0);
        }
        int p = (n << 10) + (y0 + w) * 32 + px;
        #pragma unroll
        for (int r = 0; r < 4; ++r) {
            int t9 = lg * 4 + r;
            if (t9 < 9) s9[(t9 << 18) + p] = sp[r];
        }
    }
}

// ---------------- c2 (I=64): 4-row tiles, split-K, both halves reg-prefetched ----------------
__global__ __launch_bounds__(256, 6) void c2_kernel(
        const unsigned short* __restrict__ in_, const short* __restrict__ wt,
        const float* __restrict__ bias, unsigned short* __restrict__ out_) {
    __shared__ __align__(16) short smem[6 * 34 * 40];   // 16320 B
    const int n = blockIdx.x, y0 = blockIdx.y * 4;
    const int tid = threadIdx.x, w = tid >> 6, l = tid & 63;
    const int lx = l & 15, lg = l >> 4;

    short8 r0[4], r1[4];
    int pxv[4], qcv[4];
    #pragma unroll
    for (int it = 0; it < 4; ++it) {
        int e = tid + it * 256;
        int px = e >> 2, qc = e & 3;
        pxv[it] = px; qcv[it] = qc;
        short8 v0 = (short8){0, 0, 0, 0, 0, 0, 0, 0};
        short8 v1 = v0;
        if (e < 816) {
            int r = px / 34, cx = px - r * 34;
            int gy = y0 - 1 + r, gx = cx - 1;
            if (gy >= 0 && gy < 32 && gx >= 0 && gx < 32) {
                const unsigned short* p = in_ + (n * 1024 + gy * 32 + gx) * 64 + qc * 8;
                v0 = *(const short8*)p;
                v1 = *(const short8*)(p + 32);
            }
        }
        r0[it] = v0; r1[it] = v1;
    }
    #pragma unroll
    for (int it = 0; it < 4; ++it)
        if (tid + it * 256 < 816)
            *(short8*)((char*)smem + pxv[it] * 80 + qcv[it] * 16) = r0[it];
    __syncthreads();

    f32x4 acc[4][2];
    #pragma unroll
    for (int m = 0; m < 4; ++m)
        #pragma unroll
        for (int c = 0; c < 2; ++c) acc[m][c] = (f32x4){0.f, 0.f, 0.f, 0.f};

    #pragma unroll
    for (int kx = 0; kx < 3; ++kx) {
        short8 bc[2][3];
        #pragma unroll
        for (int colf = 0; colf < 2; ++colf) {
            const int cbase = (w * 34 + kx + colf * 16 + lx) * 80 + lg * 16;
            #pragma unroll
            for (int ir = 0; ir < 3; ++ir)
                bc[colf][ir] = *(const short8*)((char*)smem + cbase + ir * (34 * 80));
        }
        #pragma unroll
        for (int m = 0; m < 4; ++m) {
            short8 af[3];
            #pragma unroll
            for (int ky = 0; ky < 3; ++ky)
                af[ky] = *(const short8*)(wt + (ky * 3 + kx) * 4096 +
                                          (lg * 64 + m * 16 + lx) * 8);
            #pragma unroll
            for (int ky = 0; ky < 3; ++ky)
                #pragma unroll
                for (int colf = 0; colf < 2; ++colf)
                    acc[m][colf] = __builtin_amdgcn_mfma_f32_16x16x32_bf16(
                        af[ky], bc[colf][ky], acc[m][colf], 0, 0, 0);
        }
    }
    __syncthreads();
    #pragma unroll
    for (int it = 0; it < 4; ++it)
        if (tid + it * 256 < 816)
            *(short8*)((char*)smem + pxv[it] * 80 + qcv[it] * 16) = r1[it];
    __syncthreads();
    #pragma unroll
    for (int kx = 0; kx < 3; ++kx) {
        short8 bc[2][3];
        #pragma unroll
        for (int colf = 0; colf < 2; ++colf) {
            const int cbase = (w * 34 + kx + colf * 16 + lx) * 80 + lg * 16;
            #pragma unroll
            for (int ir = 0; ir < 3; ++ir)
                bc[colf][ir] = *(const short8*)((char*)smem + cbase + ir * (34 * 80));
        }
        #pragma unroll
        for (int m = 0; m < 4; ++m) {
            short8 af[3];
            #pragma unroll
            for (int ky = 0; ky < 3; ++ky)
                af[ky] = *(const short8*)(wt + (ky * 3 + kx) * 4096 +
                                          ((4 + lg) * 64 + m * 16 + lx) * 8);
            #pragma unroll
            for (int ky = 0; ky < 3; ++ky)
                #pragma unroll
                for (int colf = 0; colf < 2; ++colf)
                    acc[m][colf] = __builtin_amdgcn_mfma_f32_16x16x32_bf16(
                        af[ky], bc[colf][ky], acc[m][colf], 0, 0, 0);
        }
    }

    #pragma unroll
    for (int m = 0; m < 4; ++m)
        #pragma unroll
        for (int colf = 0; colf < 2; ++colf) {
            int x = colf * 16 + lx;
            unsigned long long pk = 0ull;
            #pragma unroll
            for (int r = 0; r < 4; ++r) {
                int och = m * 16 + lg * 4 + r;
                float v = acc[m][colf][r] + bias[och];
                pk |= (unsigned long long)f2bfu(v) << (16 * r);
            }
            *(unsigned long long*)(out_ + (n * 1024 + (y0 + w) * 32 + x) * 64
                                   + m * 16 + lg * 4) = pk;
        }
}

// ---------------- a2 tap-sum + slot softmax ----------------
__global__ void a2soft_kernel(const float* __restrict__ s9, const float* __restrict__ b2,
                              float* __restrict__ outp) {
    int idx = blockIdx.x * 256 + threadIdx.x;
    if (idx >= 32 * 1024) return;
    int bb = idx >> 10, yx = idx & 1023;
    int y = yx >> 5, x = yx & 31;
    float v[8];
    float bias = b2[0];
    #pragma unroll
    for (int s = 0; s < 8; ++s) {
        int n = bb * 8 + s;
        float a = bias;
        #pragma unroll
        for (int ky = 0; ky < 3; ++ky) {
            int yy = y + ky - 1;
            if (yy < 0 || yy > 31) continue;
            #pragma unroll
            for (int kx = 0; kx < 3; ++kx) {
                int xx = x + kx - 1;
                if (xx < 0 || xx > 31) continue;
                a += s9[((ky * 3 + kx) << 18) + (n << 10) + yy * 32 + xx];
            }
        }
        v[s] = a;
    }
    float m = -3.4e38f;
    #pragma unroll
    for (int s = 0; s < 8; ++s) m = fmaxf(m, v[s]);
    float sum = 0.f;
    #pragma unroll
    for (int s = 0; s < 8; ++s) { v[s] = expf(v[s] - m); sum += v[s]; }
    float inv = 1.f / sum;
    #pragma unroll
    for (int s = 0; s < 8; ++s) outp[AOFF + ((bb * 8 + s) << 10) + yx] = v[s] * inv;
}

// ---------------- VQ via MFMA (channel-last bf16 feat) ----------------
__global__ __launch_bounds__(256) void vq_mfma_kernel(
        const unsigned short* __restrict__ featb, const float* __restrict__ codebook,
        unsigned short* __restrict__ qfeat, float* __restrict__ partial) {
    __shared__ float cbf[4096];
    __shared__ __align__(16) short cbh[4096];
    __shared__ float cn[128];
    __shared__ float red[4];
    const int tid = threadIdx.x;
    const int w = tid >> 6, l = tid & 63;
    const int lx = l & 15, lg = l >> 4;

    for (int e = tid; e < 4096; e += 256) {
        float v = codebook[e];
        cbf[e] = v;
        int code = e >> 5, d = e & 31;
        int off = (code * 32 + d) * 2;
        off ^= (code & 7) << 4;
        *(short*)((char*)cbh + off) = (short)f2bfu(v);
    }
    __syncthreads();
    if (tid < 128) {
        float s = 0.f;
        #pragma unroll
        for (int c = 0; c < 32; ++c) { float v = cbf[tid * 32 + c]; s = fmaf(v, v, s); }
        cn[tid] = s;
    }
    short8 af[8];
    #pragma unroll
    for (int m = 0; m < 8; ++m) {
        int code = m * 16 + lx;
        int off = (code * 32 + lg * 8) * 2;
        off ^= (code & 7) << 4;
        af[m] = *(const short8*)((char*)cbh + off);
    }
    __syncthreads();
    float cnh[8][4];
    #pragma unroll
    for (int m = 0; m < 8; ++m)
        #pragma unroll
        for (int r = 0; r < 4; ++r)
            cnh[m][r] = 0.5f * cn[m * 16 + lg * 4 + r];

    const int n = blockIdx.x >> 2;
    const int yxw = (blockIdx.x & 3) * 256 + w * 64;
    float lloss = 0.f;

    #pragma unroll 1
    for (int pxg = 0; pxg < 4; ++pxg) {
        int yx = yxw + pxg * 16 + lx;
        short8 bbs = *(const short8*)(featb + (n * 1024 + yx) * 32 + lg * 8);
        f32x4 S[8];
        #pragma unroll
        for (int m = 0; m < 8; ++m)
            S[m] = __builtin_amdgcn_mfma_f32_16x16x32_bf16(
                af[m], bbs, (f32x4){0.f, 0.f, 0.f, 0.f}, 0, 0, 0);
        float bestv = -3.4e38f; int besti = 0;
        #pragma unroll
        for (int m = 0; m < 8; ++m)
            #pragma unroll
            for (int r = 0; r < 4; ++r) {
                float v = S[m][r] - cnh[m][r];
                int code = m * 16 + lg * 4 + r;
                if (v > bestv) { bestv = v; besti = code; }
            }
        #pragma unroll
        for (int d = 16; d < 64; d <<= 1) {
            float ov = __shfl_xor(bestv, d);
            int oi = __shfl_xor(besti, d);
            if (ov > bestv || (ov == bestv && oi < besti)) { bestv = ov; besti = oi; }
        }
        int offq = (besti * 32 + lg * 8) * 2;
        offq ^= (besti & 7) << 4;
        short8 qh = *(const short8*)((char*)cbh + offq);
        *(short8*)(qfeat + (n * 1024 + yx) * 32 + lg * 8) = qh;
        const float* qf = &cbf[besti * 32 + lg * 8];
        #pragma unroll
        for (int j = 0; j < 8; ++j) {
            float fv = bf2f((unsigned short)bbs[j]);
            float dd = qf[j] - fv;
            lloss = fmaf(dd, dd, lloss);
        }
    }
    for (int off = 32; off > 0; off >>= 1) lloss += __shfl_down(lloss, off);
    if (l == 0) red[w] = lloss;
    __syncthreads();
    if (tid == 0) partial[blockIdx.x] = (red[0] + red[1]) + (red[2] + red[3]);
}

// ---------------- recon (channel-last colors) ----------------
__global__ __launch_bounds__(256) void recon_kernel(
        const unsigned short* __restrict__ colors, float* __restrict__ outp) {
    const int b = blockIdx.x, y8 = blockIdx.y;
    const int tid = threadIdx.x;
    const int yxl = tid & 127, vh = tid >> 7;
    const int yx = y8 * 128 + yxl;
    float acc[32];
    #pragma unroll
    for (int v = 0; v < 32; ++v) acc[v] = 0.f;
    #pragma unroll 1
    for (int s = 0; s < 8; ++s) {
        float a = outp[AOFF + ((b * 8 + s) << 10) + yx];
        const unsigned short* cp = colors + ((b * 8 + s) * 1024 + yx) * 64 + vh * 32;
        #pragma unroll
        for (int k = 0; k < 4; ++k) {
            short8 v8 = *(const short8*)(cp + k * 8);
            #pragma unroll
            for (int j = 0; j < 8; ++j)
                acc[k * 8 + j] = fmaf(a, bf2f((unsigned short)v8[j]), acc[k * 8 + j]);
        }
    }
    #pragma unroll
    for (int v = 0; v < 32; ++v)
        outp[(b * 64 + vh * 32 + v) * 1024 + yx] = acc[v];
}

__global__ void loss_kernel(const float* __restrict__ partial, float* __restrict__ outp) {
    __shared__ float red[4];
    int t = threadIdx.x;
    float s = 0.f;
    for (int i = t; i < 1024; i += 256) s += partial[i];
    for (int o = 32; o > 0; o >>= 1) s += __shfl_down(s, o);
    if ((t & 63) == 0) red[t >> 6] = s;
    __syncthreads();
    if (t == 0) outp[LOFF] = 1.25f * ((red[0] + red[1]) + (red[2] + red[3])) / 8388608.0f;
}

extern "C" void kernel_launch(void* const* d_in, const int* in_sizes, int n_in,
                              void* d_out, int out_size, void* d_ws, size_t ws_size,
                              hipStream_t stream) {
    const float* latent  = (const float*)d_in[0];
    const float* pos_w   = (const float*)d_in[1];
    const float* pos_b   = (const float*)d_in[2];
    const float* ct1_w   = (const float*)d_in[3];
    const float* ct1_b   = (const float*)d_in[4];
    const float* ct2_w   = (const float*)d_in[5];
    const float* ct2_b   = (const float*)d_in[6];
    const float* codebook= (const float*)d_in[7];
    const float* c1_w    = (const float*)d_in[8];
    const float* c1_b    = (const float*)d_in[9];
    const float* c2_w    = (const float*)d_in[10];
    const float* c2_b    = (const float*)d_in[11];
    const float* a1_w    = (const float*)d_in[12];
    const float* a1_b    = (const float*)d_in[13];
    const float* a2_w    = (const float*)d_in[14];
    const float* a2_b    = (const float*)d_in[15];
    float* out = (float*)d_out;

    float* ws     = (float*)d_ws;
    unsigned short* featb = (unsigned short*)ws;   // 8388608 ushorts
    float* s9     = ws + 8388608;            // 2359296
    float* tapabc = s9 + 2359296;            // 4800
    float* P      = tapabc + 4800;           // 65536
    float* M      = P + 65536;               // 409600
    float* partial= M + 409600;              // 1024
    float* Wsum   = partial + 1024;          // 204800
    short* wtall  = (short*)(Wsum + 204800); // 124928 shorts
    short* wtA    = wtall;
    short* wtC1   = wtall + 18432;
    short* wtC2   = wtall + 36864;
    short* wtT2   = wtall + 73728;
    unsigned short* tmpb    = (unsigned short*)(wtall + 124928);  // c1out: 16777216
    unsigned short* qfeatb  = tmpb + 16777216;                    // 8388608
    unsigned short* colorsb = qfeatb + 8388608;                   // 16777216

    tapabc_kernel<<<25, 192, 0, stream>>>(pos_w, pos_b, ct1_w, tapabc);
    pfill_kernel<<<64, 1024, 0, stream>>>(tapabc, ct1_b, P);
    prep_ws_kernel<<<1288, 256, 0, stream>>>(ct1_w, a1_w, c1_w, c2_w, ct2_w, Wsum, wtall);
    m_kernel<<<dim3(256, 25), 64, 0, stream>>>(latent, Wsum, M);

    conv5_kernel<<<dim3(256, 8), 256, 0, stream>>>(M, P, wtT2, ct2_b, featb);
    // alpha head: a1 conv + MFMA a2 projection -> s9 -> softmax
    conv3a2_kernel<<<dim3(256, 8), 256, 0, stream>>>(featb, wtA, a1_b, a2_w, s9);
    a2soft_kernel<<<128, 256, 0, stream>>>(s9, a2_b, out);
    // VQ
    vq_mfma_kernel<<<1024, 256, 0, stream>>>(featb, codebook, qfeatb, partial);
    // color head
    conv3_kernel<1><<<dim3(256, 8), 256, 0, stream>>>(qfeatb, wtC1, c1_b, tmpb);
    c2_kernel<<<dim3(256, 8), 256, 0, stream>>>(tmpb, wtC2, c2_b, colorsb);
    recon_kernel<<<dim3(32, 8), 256, 0, stream>>>(colorsb, out);
    loss_kernel<<<1, 256, 0, stream>>>(partial, out);
}

// Round 19
// 209.058 us; speedup vs baseline: 1.2888x; 1.2888x over previous
//
#include <hip/hip_runtime.h>
#include <math.h>

#define AOFF 2097152   // recon = 32*64*1024 floats, alphas follow
#define LOFF 2359296   // AOFF + 32*8*1024

typedef __attribute__((ext_vector_type(8))) short short8;
typedef __attribute__((ext_vector_type(4))) float f32x4;

__device__ __forceinline__ int clsf(int v) { return v < 2 ? v : (v > 29 ? v - 27 : 2); }

__device__ __forceinline__ unsigned int f2bfu(float x) {
    unsigned int u = __float_as_uint(x);
    return (u + 0x7FFFu + ((u >> 16) & 1u)) >> 16;
}
__device__ __forceinline__ unsigned int cvt2(float a, float b) {
    return f2bfu(a) | (f2bfu(b) << 16);
}
__device__ __forceinline__ float bf2f(unsigned short u) {
    return __uint_as_float(((unsigned int)u) << 16);
}

// ---------------- tapabc: per-tap dot with affine pos coeffs (w1 staged in LDS) ----------------
__global__ void tapabc_kernel(const float* __restrict__ pw, const float* __restrict__ pb,
                              const float* __restrict__ w1, float* __restrict__ tapabc) {
    __shared__ float A3[384];
    __shared__ float wl[8192];
    int tap = blockIdx.x, t = threadIdx.x;     // 192 threads
    if (t < 128) {
        float p0 = pw[t * 4], p1 = pw[t * 4 + 1], p2 = pw[t * 4 + 2], p3 = pw[t * 4 + 3];
        A3[t] = p2 + p3 + pb[t];
        A3[128 + t] = p0 - p2;
        A3[256 + t] = p1 - p3;
    }
    for (int e = t; e < 8192; e += 192) wl[e] = w1[e * 25 + tap];
    __syncthreads();
    int o = t & 63, comp = t >> 6;
    const float* a = A3 + comp * 128;
    float s = 0.f;
    for (int i = 0; i < 128; ++i) s = fmaf(wl[i * 64 + o], a[i], s);
    tapabc[(tap * 64 + o) * 3 + comp] = s;
}

// ---------------- P fill: channel-PAIR interleaved float2 layout ----------------
__global__ void pfill_kernel(const float* __restrict__ tapabc, const float* __restrict__ b1,
                             float* __restrict__ P2) {
    __shared__ float uv[75];
    int o = blockIdx.x, t = threadIdx.x;       // 1024 threads
    if (t < 75) {
        int cls = t / 3, comp = t % 3;
        int cy = cls / 5, cx = cls % 5;
        const int klo[5] = {2, 1, 0, 0, 0}, khi[5] = {4, 4, 4, 3, 2};
        const float inv31 = 1.f / 31.f;
        float s = (comp == 0) ? b1[o] : 0.f;
        for (int ky = klo[cy]; ky <= khi[cy]; ++ky)
            for (int kx = klo[cx]; kx <= khi[cx]; ++kx) {
                int tap = (4 - ky) * 5 + (4 - kx);
                const float* tp = &tapabc[(tap * 64 + o) * 3];
                if (comp == 0) s += tp[0] + tp[1] * (ky - 2) * inv31 + tp[2] * (kx - 2) * inv31;
                else if (comp == 1) s += tp[1] * inv31;
                else s += tp[2] * inv31;
            }
        uv[t] = s;
    }
    __syncthreads();
    int y = t >> 5, x = t & 31;
    int cls = clsf(y) * 5 + clsf(x);
    float val = uv[cls * 3] + uv[cls * 3 + 1] * y + uv[cls * 3 + 2] * x;
    P2[((o >> 1) << 11) + (t << 1) + (o & 1)] = val;
}

// ---------------- merged: Wsum (gid < 204800) + weight prep (rest) ----------------
__global__ void prep_ws_kernel(const float* __restrict__ w1,
                               const float* __restrict__ a1w, const float* __restrict__ c1w,
                               const float* __restrict__ c2w, const float* __restrict__ ct2w,
                               float* __restrict__ Wsum, short* __restrict__ wtall) {
    int gid = blockIdx.x * 256 + threadIdx.x;
    const int klo[5] = {2, 1, 0, 0, 0}, khi[5] = {4, 4, 4, 3, 2};
    if (gid < 204800) {
        int idx = gid;
        int cls = idx >> 13;
        int i = (idx >> 6) & 127;
        int o = idx & 63;
        int cy = cls / 5, cx = cls % 5;
        float s = 0.f;
        for (int ky = klo[cy]; ky <= khi[cy]; ++ky)
            for (int kx = klo[cx]; kx <= khi[cx]; ++kx)
                s += w1[(i * 64 + o) * 25 + (4 - ky) * 5 + (4 - kx)];
        Wsum[idx] = s;
        return;
    }
    gid -= 204800;
    if (gid < 36864) {                                  // a1 / c1 : I=32,O=64
        const float* src = gid < 18432 ? a1w : c1w;
        int idx = gid < 18432 ? gid : gid - 18432;
        int j = idx & 7, fi = idx >> 3;
        int o = fi % 64, g = (fi / 64) & 3, t = fi / 256;
        int i = g * 8 + j;
        wtall[gid] = (short)f2bfu(src[(o * 32 + i) * 9 + (t / 3) * 3 + (t % 3)]);
    } else if (gid < 73728) {                           // c2 : I=64,O=64
        int idx = gid - 36864;
        int j = idx & 7, fi = idx >> 3;
        int o = fi % 64, g = (fi / 64) & 3, ks = (fi / 256) & 1, t = fi / 512;
        int i = ks * 32 + g * 8 + j;
        wtall[gid] = (short)f2bfu(c2w[(o * 64 + i) * 9 + (t / 3) * 3 + (t % 3)]);
    } else if (gid < 124928) {                          // convT2 : flipped 5x5
        int idx = gid - 73728;
        int j = idx & 7, fi = idx >> 3;
        int o = fi & 31, g = (fi >> 5) & 3, ks = (fi >> 7) & 1, t = fi >> 8;
        int i = ks * 32 + g * 8 + j;
        int ky = t / 5, kx = t % 5;
        wtall[gid] = (short)f2bfu(ct2w[((i * 32 + o) * 5 + (4 - ky)) * 5 + (4 - kx)]);
    }
}

// ---------------- M[n][cls][o] ----------------
__global__ void m_kernel(const float* __restrict__ latent, const float* __restrict__ Wsum,
                         float* __restrict__ M) {
    int n = blockIdx.x, cls = blockIdx.y, o = threadIdx.x;
    const float* l = &latent[n * 128];
    const float* w = &Wsum[cls * 8192 + o];
    float a0 = 0.f, a1 = 0.f;
    for (int i = 0; i < 128; i += 2) {
        a0 = fmaf(l[i], w[i * 64], a0);
        a1 = fmaf(l[i + 1], w[(i + 1) * 64], a1);
    }
    M[(n * 25 + cls) * 64 + o] = a0 + a1;
}

// ---------------- conv5 (convT2): 8-row tiles, split-K, padded LDS (R12-proven) ----------------
__global__ __launch_bounds__(256) void conv5_kernel(
        const float* __restrict__ M, const float* __restrict__ P2,
        const short* __restrict__ wt, const float* __restrict__ b2,
        unsigned short* __restrict__ featb) {
    __shared__ __align__(16) short tile[12 * 36 * 40];  // 34560 B
    __shared__ float Ml[1600];
    const int n = blockIdx.x, y0 = blockIdx.y * 8;
    const int tid = threadIdx.x, w = tid >> 6, l = tid & 63;
    const int lx = l & 15, lg = l >> 4;

    for (int e = tid; e < 1600; e += 256) Ml[e] = M[n * 1600 + e];
    __syncthreads();

    f32x4 acc[2][2][2];
    #pragma unroll
    for (int m = 0; m < 2; ++m)
        #pragma unroll
        for (int q = 0; q < 2; ++q)
            #pragma unroll
            for (int c = 0; c < 2; ++c) acc[m][q][c] = (f32x4){0.f, 0.f, 0.f, 0.f};

    #pragma unroll 1
    for (int ks = 0; ks < 2; ++ks) {
        if (ks) __syncthreads();
        for (int e = tid; e < 6912; e += 256) {
            int cx = e % 36;
            int q = e / 36;
            int ipl = q & 15;
            int r = q >> 4;
            int gy = y0 - 2 + r, gx = cx - 2;
            unsigned int pack = 0u;
            if (gy >= 0 && gy < 32 && gx >= 0 && gx < 32) {
                int cls = clsf(gy) * 5 + clsf(gx);
                int pp = gy * 32 + gx;
                float2 pv = ((const float2*)P2)[((ks * 16 + ipl) << 10) + pp];
                float2 ml = ((const float2*)Ml)[cls * 32 + ks * 16 + ipl];
                pack = cvt2(fmaxf(ml.x + pv.x, 0.f), fmaxf(ml.y + pv.y, 0.f));
            }
            *(unsigned int*)((char*)tile + (r * 36 + cx) * 80 + ipl * 4) = pack;
        }
        __syncthreads();
        for (int kx = 0; kx < 5; ++kx) {
            short8 af[5][2];
            #pragma unroll
            for (int ky = 0; ky < 5; ++ky)
                #pragma unroll
                for (int m = 0; m < 2; ++m)
                    af[ky][m] = *(const short8*)(wt + (ky * 5 + kx) * 2048 +
                                                 ((ks * 4 + lg) * 32 + m * 16 + lx) * 8);
            #pragma unroll
            for (int colf = 0; colf < 2; ++colf) {
                const int cbase = ((2 * w) * 36 + kx + colf * 16 + lx) * 80 + lg * 16;
                short8 bc[6];
                #pragma unroll
                for (int ir = 0; ir < 6; ++ir)
                    bc[ir] = *(const short8*)((char*)tile + cbase + ir * (36 * 80));
                #pragma unroll
                for (int ky = 0; ky < 5; ++ky)
                    #pragma unroll
                    for (int q = 0; q < 2; ++q)
                        #pragma unroll
                        for (int m = 0; m < 2; ++m)
                            acc[m][q][colf] = __builtin_amdgcn_mfma_f32_16x16x32_bf16(
                                af[ky][m], bc[q + ky], acc[m][q][colf], 0, 0, 0);
            }
        }
    }

    #pragma unroll
    for (int m = 0; m < 2; ++m)
        #pragma unroll
        for (int q = 0; q < 2; ++q)
            #pragma unroll
            for (int colf = 0; colf < 2; ++colf) {
                int yl = 2 * w + q, x = colf * 16 + lx;
                unsigned long long pk = 0ull;
                #pragma unroll
                for (int r = 0; r < 4; ++r) {
                    int och = m * 16 + lg * 4 + r;
                    float v = fmaxf(acc[m][q][colf][r] + b2[och], 0.f);
                    pk |= (unsigned long long)f2bfu(v) << (16 * r);
                }
                *(unsigned long long*)(featb + (n * 1024 + (y0 + yl) * 32 + x) * 32
                                       + m * 16 + lg * 4) = pk;
            }
}

// ---------------- conv3 (I=32): 4-row tiles, 1 row/wave (c1 path) ----------------
template<int ACT>
__global__ __launch_bounds__(256, 6) void conv3_kernel(
        const unsigned short* __restrict__ in_, const short* __restrict__ wt,
        const float* __restrict__ bias, unsigned short* __restrict__ out_) {
    __shared__ __align__(16) short smem[6 * 34 * 40];   // 16320 B
    const int n = blockIdx.x, y0 = blockIdx.y * 4;
    const int tid = threadIdx.x, w = tid >> 6, l = tid & 63;
    const int lx = l & 15, lg = l >> 4;

    for (int e = tid; e < 816; e += 256) {
        int px = e >> 2, qc = e & 3;
        int r = px / 34, cx = px - r * 34;
        int gy = y0 - 1 + r, gx = cx - 1;
        short8 v8 = (short8){0, 0, 0, 0, 0, 0, 0, 0};
        if (gy >= 0 && gy < 32 && gx >= 0 && gx < 32)
            v8 = *(const short8*)(in_ + (n * 1024 + gy * 32 + gx) * 32 + qc * 8);
        *(short8*)((char*)smem + px * 80 + qc * 16) = v8;
    }
    __syncthreads();

    f32x4 acc[4][2];
    #pragma unroll
    for (int m = 0; m < 4; ++m)
        #pragma unroll
        for (int c = 0; c < 2; ++c) acc[m][c] = (f32x4){0.f, 0.f, 0.f, 0.f};

    #pragma unroll
    for (int kx = 0; kx < 3; ++kx) {
        short8 bc[2][3];
        #pragma unroll
        for (int colf = 0; colf < 2; ++colf) {
            const int cbase = (w * 34 + kx + colf * 16 + lx) * 80 + lg * 16;
            #pragma unroll
            for (int ir = 0; ir < 3; ++ir)
                bc[colf][ir] = *(const short8*)((char*)smem + cbase + ir * (34 * 80));
        }
        #pragma unroll
        for (int m = 0; m < 4; ++m) {
            short8 af[3];
            #pragma unroll
            for (int ky = 0; ky < 3; ++ky)
                af[ky] = *(const short8*)(wt + (ky * 3 + kx) * 2048 +
                                          (lg * 64 + m * 16 + lx) * 8);
            #pragma unroll
            for (int ky = 0; ky < 3; ++ky)
                #pragma unroll
                for (int colf = 0; colf < 2; ++colf)
                    acc[m][colf] = __builtin_amdgcn_mfma_f32_16x16x32_bf16(
                        af[ky], bc[colf][ky], acc[m][colf], 0, 0, 0);
        }
    }

    #pragma unroll
    for (int m = 0; m < 4; ++m)
        #pragma unroll
        for (int colf = 0; colf < 2; ++colf) {
            int x = colf * 16 + lx;
            unsigned long long pk = 0ull;
            #pragma unroll
            for (int r = 0; r < 4; ++r) {
                int och = m * 16 + lg * 4 + r;
                float v = acc[m][colf][r] + bias[och];
                if (ACT == 1) v = v / (1.f + expf(-v));
                pk |= (unsigned long long)f2bfu(v) << (16 * r);
            }
            *(unsigned long long*)(out_ + (n * 1024 + (y0 + w) * 32 + x) * 64
                                   + m * 16 + lg * 4) = pk;
        }
}

// ---------------- conv3a2: a1 conv + a2 projection via MFMA ----------------
__global__ __launch_bounds__(256, 6) void conv3a2_kernel(
        const unsigned short* __restrict__ in_, const short* __restrict__ wt,
        const float* __restrict__ bias, const float* __restrict__ a2w,
        float* __restrict__ s9) {
    __shared__ __align__(16) short smem[8192];   // 16384 B: staging / repack
    __shared__ float wl9[576];
    const int n = blockIdx.x, y0 = blockIdx.y * 4;
    const int tid = threadIdx.x, w = tid >> 6, l = tid & 63;
    const int lx = l & 15, lg = l >> 4;

    for (int e = tid; e < 576; e += 256) wl9[e] = a2w[e];
    for (int e = tid; e < 816; e += 256) {
        int px = e >> 2, qc = e & 3;
        int r = px / 34, cx = px - r * 34;
        int gy = y0 - 1 + r, gx = cx - 1;
        short8 v8 = (short8){0, 0, 0, 0, 0, 0, 0, 0};
        if (gy >= 0 && gy < 32 && gx >= 0 && gx < 32)
            v8 = *(const short8*)(in_ + (n * 1024 + gy * 32 + gx) * 32 + qc * 8);
        *(short8*)((char*)smem + px * 80 + qc * 16) = v8;
    }
    __syncthreads();

    f32x4 acc[4][2];
    #pragma unroll
    for (int m = 0; m < 4; ++m)
        #pragma unroll
        for (int c = 0; c < 2; ++c) acc[m][c] = (f32x4){0.f, 0.f, 0.f, 0.f};

    #pragma unroll
    for (int kx = 0; kx < 3; ++kx) {
        short8 bc[2][3];
        #pragma unroll
        for (int colf = 0; colf < 2; ++colf) {
            const int cbase = (w * 34 + kx + colf * 16 + lx) * 80 + lg * 16;
            #pragma unroll
            for (int ir = 0; ir < 3; ++ir)
                bc[colf][ir] = *(const short8*)((char*)smem + cbase + ir * (34 * 80));
        }
        #pragma unroll
        for (int m = 0; m < 4; ++m) {
            short8 af[3];
            #pragma unroll
            for (int ky = 0; ky < 3; ++ky)
                af[ky] = *(const short8*)(wt + (ky * 3 + kx) * 2048 +
                                          (lg * 64 + m * 16 + lx) * 8);
            #pragma unroll
            for (int ky = 0; ky < 3; ++ky)
                #pragma unroll
                for (int colf = 0; colf < 2; ++colf)
                    acc[m][colf] = __builtin_amdgcn_mfma_f32_16x16x32_bf16(
                        af[ky], bc[colf][ky], acc[m][colf], 0, 0, 0);
        }
    }

    short8 af9[2];
    #pragma unroll
    for (int ks = 0; ks < 2; ++ks)
        #pragma unroll
        for (int j = 0; j < 8; ++j) {
            int ch = ks * 32 + lg * 8 + j;
            float v = (lx < 9) ? wl9[ch * 9 + lx] : 0.f;
            af9[ks][j] = (short)f2bfu(v);
        }

    __syncthreads();
    char* base = (char*)smem + w * 4096;
    #pragma unroll
    for (int m = 0; m < 4; ++m)
        #pragma unroll
        for (int colf = 0; colf < 2; ++colf) {
            int px = colf * 16 + lx;
            unsigned long long pk = 0ull;
            #pragma unroll
            for (int r = 0; r < 4; ++r) {
                int och = m * 16 + lg * 4 + r;
                float v = acc[m][colf][r] + bias[och];
                v = v / (1.f + expf(-v));
                pk |= (unsigned long long)f2bfu(v) << (16 * r);
            }
            int slot = 2 * m + (lg >> 1);
            int off = px * 128 + (((slot ^ (px & 7)) << 4)) + (lg & 1) * 8;
            *(unsigned long long*)(base + off) = pk;
        }
    __syncthreads();

    #pragma unroll
    for (int colf = 0; colf < 2; ++colf) {
        int px = colf * 16 + lx;
        f32x4 sp = (f32x4){0.f, 0.f, 0.f, 0.f};
        #pragma unroll
        for (int ks = 0; ks < 2; ++ks) {
            int slot = ks * 4 + lg;
            short8 bf = *(const short8*)(base + px * 128 + ((slot ^ (px & 7)) << 4));
            sp = __builtin_amdgcn_mfma_f32_16x16x32_bf16(af9[ks], bf, sp, 0, 0, 0);
        }
        int p = (n << 10) + (y0 + w) * 32 + px;
        #pragma unroll
        for (int r = 0; r < 4; ++r) {
            int t9 = lg * 4 + r;
            if (t9 < 9) s9[(t9 << 18) + p] = sp[r];
        }
    }
}

// ---------------- c2 (I=64): 8-row tiles, both K-halves reg-prefetched (R13-proven) ----------------
__global__ __launch_bounds__(256) void c2_kernel(
        const unsigned short* __restrict__ in_, const short* __restrict__ wt,
        const float* __restrict__ bias, unsigned short* __restrict__ out_) {
    __shared__ __align__(16) short smem[10 * 34 * 40];   // 27200 B
    const int n = blockIdx.x, y0 = blockIdx.y * 8;
    const int tid = threadIdx.x, w = tid >> 6, l = tid & 63;
    const int lx = l & 15, lg = l >> 4;

    short8 r0[6], r1[6];
    int pxv[6], qcv[6];
    #pragma unroll
    for (int it = 0; it < 6; ++it) {
        int e = tid + it * 256;
        int px = e >> 2, qc = e & 3;
        pxv[it] = px; qcv[it] = qc;
        short8 v0 = (short8){0, 0, 0, 0, 0, 0, 0, 0};
        short8 v1 = v0;
        if (e < 1360) {
            int r = px / 34, cx = px - r * 34;
            int gy = y0 - 1 + r, gx = cx - 1;
            if (gy >= 0 && gy < 32 && gx >= 0 && gx < 32) {
                const unsigned short* p = in_ + (n * 1024 + gy * 32 + gx) * 64 + qc * 8;
                v0 = *(const short8*)p;
                v1 = *(const short8*)(p + 32);
            }
        }
        r0[it] = v0; r1[it] = v1;
    }
    #pragma unroll
    for (int it = 0; it < 6; ++it)
        if (tid + it * 256 < 1360)
            *(short8*)((char*)smem + pxv[it] * 80 + qcv[it] * 16) = r0[it];
    __syncthreads();

    f32x4 acc[4][2][2];
    #pragma unroll
    for (int m = 0; m < 4; ++m)
        #pragma unroll
        for (int q = 0; q < 2; ++q)
            #pragma unroll
            for (int c = 0; c < 2; ++c) acc[m][q][c] = (f32x4){0.f, 0.f, 0.f, 0.f};

    #pragma unroll
    for (int kx = 0; kx < 3; ++kx) {
        short8 af[3][4];
        #pragma unroll
        for (int ky = 0; ky < 3; ++ky)
            #pragma unroll
            for (int m = 0; m < 4; ++m)
                af[ky][m] = *(const short8*)(wt + (ky * 3 + kx) * 4096 +
                                             (lg * 64 + m * 16 + lx) * 8);
        #pragma unroll
        for (int colf = 0; colf < 2; ++colf) {
            const int cbase = ((2 * w) * 34 + kx + colf * 16 + lx) * 80 + lg * 16;
            short8 bc[4];
            #pragma unroll
            for (int ir = 0; ir < 4; ++ir)
                bc[ir] = *(const short8*)((char*)smem + cbase + ir * (34 * 80));
            #pragma unroll
            for (int ky = 0; ky < 3; ++ky)
                #pragma unroll
                for (int q = 0; q < 2; ++q)
                    #pragma unroll
                    for (int m = 0; m < 4; ++m)
                        acc[m][q][colf] = __builtin_amdgcn_mfma_f32_16x16x32_bf16(
                            af[ky][m], bc[q + ky], acc[m][q][colf], 0, 0, 0);
        }
    }
    __syncthreads();
    #pragma unroll
    for (int it = 0; it < 6; ++it)
        if (tid + it * 256 < 1360)
            *(short8*)((char*)smem + pxv[it] * 80 + qcv[it] * 16) = r1[it];
    __syncthreads();
    #pragma unroll
    for (int kx = 0; kx < 3; ++kx) {
        short8 af[3][4];
        #pragma unroll
        for (int ky = 0; ky < 3; ++ky)
            #pragma unroll
            for (int m = 0; m < 4; ++m)
                af[ky][m] = *(const short8*)(wt + (ky * 3 + kx) * 4096 +
                                             ((4 + lg) * 64 + m * 16 + lx) * 8);
        #pragma unroll
        for (int colf = 0; colf < 2; ++colf) {
            const int cbase = ((2 * w) * 34 + kx + colf * 16 + lx) * 80 + lg * 16;
            short8 bc[4];
            #pragma unroll
            for (int ir = 0; ir < 4; ++ir)
                bc[ir] = *(const short8*)((char*)smem + cbase + ir * (34 * 80));
            #pragma unroll
            for (int ky = 0; ky < 3; ++ky)
                #pragma unroll
                for (int q = 0; q < 2; ++q)
                    #pragma unroll
                    for (int m = 0; m < 4; ++m)
                        acc[m][q][colf] = __builtin_amdgcn_mfma_f32_16x16x32_bf16(
                            af[ky][m], bc[q + ky], acc[m][q][colf], 0, 0, 0);
        }
    }

    #pragma unroll
    for (int m = 0; m < 4; ++m)
        #pragma unroll
        for (int q = 0; q < 2; ++q)
            #pragma unroll
            for (int colf = 0; colf < 2; ++colf) {
                int yl = 2 * w + q, x = colf * 16 + lx;
                unsigned long long pk = 0ull;
                #pragma unroll
                for (int r = 0; r < 4; ++r) {
                    int och = m * 16 + lg * 4 + r;
                    float v = acc[m][q][colf][r] + bias[och];
                    pk |= (unsigned long long)f2bfu(v) << (16 * r);
                }
                *(unsigned long long*)(out_ + (n * 1024 + (y0 + yl) * 32 + x) * 64
                                       + m * 16 + lg * 4) = pk;
            }
}

// ---------------- a2 tap-sum + slot softmax ----------------
__global__ void a2soft_kernel(const float* __restrict__ s9, const float* __restrict__ b2,
                              float* __restrict__ outp) {
    int idx = blockIdx.x * 256 + threadIdx.x;
    if (idx >= 32 * 1024) return;
    int bb = idx >> 10, yx = idx & 1023;
    int y = yx >> 5, x = yx & 31;
    float v[8];
    float bias = b2[0];
    #pragma unroll
    for (int s = 0; s < 8; ++s) {
        int n = bb * 8 + s;
        float a = bias;
        #pragma unroll
        for (int ky = 0; ky < 3; ++ky) {
            int yy = y + ky - 1;
            if (yy < 0 || yy > 31) continue;
            #pragma unroll
            for (int kx = 0; kx < 3; ++kx) {
                int xx = x + kx - 1;
                if (xx < 0 || xx > 31) continue;
                a += s9[((ky * 3 + kx) << 18) + (n << 10) + yy * 32 + xx];
            }
        }
        v[s] = a;
    }
    float m = -3.4e38f;
    #pragma unroll
    for (int s = 0; s < 8; ++s) m = fmaxf(m, v[s]);
    float sum = 0.f;
    #pragma unroll
    for (int s = 0; s < 8; ++s) { v[s] = expf(v[s] - m); sum += v[s]; }
    float inv = 1.f / sum;
    #pragma unroll
    for (int s = 0; s < 8; ++s) outp[AOFF + ((bb * 8 + s) << 10) + yx] = v[s] * inv;
}

// ---------------- VQ via MFMA (channel-last bf16 feat) ----------------
__global__ __launch_bounds__(256) void vq_mfma_kernel(
        const unsigned short* __restrict__ featb, const float* __restrict__ codebook,
        unsigned short* __restrict__ qfeat, float* __restrict__ partial) {
    __shared__ float cbf[4096];
    __shared__ __align__(16) short cbh[4096];
    __shared__ float cn[128];
    __shared__ float red[4];
    const int tid = threadIdx.x;
    const int w = tid >> 6, l = tid & 63;
    const int lx = l & 15, lg = l >> 4;

    for (int e = tid; e < 4096; e += 256) {
        float v = codebook[e];
        cbf[e] = v;
        int code = e >> 5, d = e & 31;
        int off = (code * 32 + d) * 2;
        off ^= (code & 7) << 4;
        *(short*)((char*)cbh + off) = (short)f2bfu(v);
    }
    __syncthreads();
    if (tid < 128) {
        float s = 0.f;
        #pragma unroll
        for (int c = 0; c < 32; ++c) { float v = cbf[tid * 32 + c]; s = fmaf(v, v, s); }
        cn[tid] = s;
    }
    short8 af[8];
    #pragma unroll
    for (int m = 0; m < 8; ++m) {
        int code = m * 16 + lx;
        int off = (code * 32 + lg * 8) * 2;
        off ^= (code & 7) << 4;
        af[m] = *(const short8*)((char*)cbh + off);
    }
    __syncthreads();
    float cnh[8][4];
    #pragma unroll
    for (int m = 0; m < 8; ++m)
        #pragma unroll
        for (int r = 0; r < 4; ++r)
            cnh[m][r] = 0.5f * cn[m * 16 + lg * 4 + r];

    const int n = blockIdx.x >> 2;
    const int yxw = (blockIdx.x & 3) * 256 + w * 64;
    float lloss = 0.f;

    #pragma unroll 1
    for (int pxg = 0; pxg < 4; ++pxg) {
        int yx = yxw + pxg * 16 + lx;
        short8 bbs = *(const short8*)(featb + (n * 1024 + yx) * 32 + lg * 8);
        f32x4 S[8];
        #pragma unroll
        for (int m = 0; m < 8; ++m)
            S[m] = __builtin_amdgcn_mfma_f32_16x16x32_bf16(
                af[m], bbs, (f32x4){0.f, 0.f, 0.f, 0.f}, 0, 0, 0);
        float bestv = -3.4e38f; int besti = 0;
        #pragma unroll
        for (int m = 0; m < 8; ++m)
            #pragma unroll
            for (int r = 0; r < 4; ++r) {
                float v = S[m][r] - cnh[m][r];
                int code = m * 16 + lg * 4 + r;
                if (v > bestv) { bestv = v; besti = code; }
            }
        #pragma unroll
        for (int d = 16; d < 64; d <<= 1) {
            float ov = __shfl_xor(bestv, d);
            int oi = __shfl_xor(besti, d);
            if (ov > bestv || (ov == bestv && oi < besti)) { bestv = ov; besti = oi; }
        }
        int offq = (besti * 32 + lg * 8) * 2;
        offq ^= (besti & 7) << 4;
        short8 qh = *(const short8*)((char*)cbh + offq);
        *(short8*)(qfeat + (n * 1024 + yx) * 32 + lg * 8) = qh;
        const float* qf = &cbf[besti * 32 + lg * 8];
        #pragma unroll
        for (int j = 0; j < 8; ++j) {
            float fv = bf2f((unsigned short)bbs[j]);
            float dd = qf[j] - fv;
            lloss = fmaf(dd, dd, lloss);
        }
    }
    for (int off = 32; off > 0; off >>= 1) lloss += __shfl_down(lloss, off);
    if (l == 0) red[w] = lloss;
    __syncthreads();
    if (tid == 0) partial[blockIdx.x] = (red[0] + red[1]) + (red[2] + red[3]);
}

// ---------------- recon (channel-last colors) ----------------
__global__ __launch_bounds__(256) void recon_kernel(
        const unsigned short* __restrict__ colors, float* __restrict__ outp) {
    const int b = blockIdx.x, y8 = blockIdx.y;
    const int tid = threadIdx.x;
    const int yxl = tid & 127, vh = tid >> 7;
    const int yx = y8 * 128 + yxl;
    float acc[32];
    #pragma unroll
    for (int v = 0; v < 32; ++v) acc[v] = 0.f;
    #pragma unroll 1
    for (int s = 0; s < 8; ++s) {
        float a = outp[AOFF + ((b * 8 + s) << 10) + yx];
        const unsigned short* cp = colors + ((b * 8 + s) * 1024 + yx) * 64 + vh * 32;
        #pragma unroll
        for (int k = 0; k < 4; ++k) {
            short8 v8 = *(const short8*)(cp + k * 8);
            #pragma unroll
            for (int j = 0; j < 8; ++j)
                acc[k * 8 + j] = fmaf(a, bf2f((unsigned short)v8[j]), acc[k * 8 + j]);
        }
    }
    #pragma unroll
    for (int v = 0; v < 32; ++v)
        outp[(b * 64 + vh * 32 + v) * 1024 + yx] = acc[v];
}

__global__ void loss_kernel(const float* __restrict__ partial, float* __restrict__ outp) {
    __shared__ float red[4];
    int t = threadIdx.x;
    float s = 0.f;
    for (int i = t; i < 1024; i += 256) s += partial[i];
    for (int o = 32; o > 0; o >>= 1) s += __shfl_down(s, o);
    if ((t & 63) == 0) red[t >> 6] = s;
    __syncthreads();
    if (t == 0) outp[LOFF] = 1.25f * ((red[0] + red[1]) + (red[2] + red[3])) / 8388608.0f;
}

extern "C" void kernel_launch(void* const* d_in, const int* in_sizes, int n_in,
                              void* d_out, int out_size, void* d_ws, size_t ws_size,
                              hipStream_t stream) {
    const float* latent  = (const float*)d_in[0];
    const float* pos_w   = (const float*)d_in[1];
    const float* pos_b   = (const float*)d_in[2];
    const float* ct1_w   = (const float*)d_in[3];
    const float* ct1_b   = (const float*)d_in[4];
    const float* ct2_w   = (const float*)d_in[5];
    const float* ct2_b   = (const float*)d_in[6];
    const float* codebook= (const float*)d_in[7];
    const float* c1_w    = (const float*)d_in[8];
    const float* c1_b    = (const float*)d_in[9];
    const float* c2_w    = (const float*)d_in[10];
    const float* c2_b    = (const float*)d_in[11];
    const float* a1_w    = (const float*)d_in[12];
    const float* a1_b    = (const float*)d_in[13];
    const float* a2_w    = (const float*)d_in[14];
    const float* a2_b    = (const float*)d_in[15];
    float* out = (float*)d_out;

    float* ws     = (float*)d_ws;
    unsigned short* featb = (unsigned short*)ws;   // 8388608 ushorts
    float* s9     = ws + 8388608;            // 2359296
    float* tapabc = s9 + 2359296;            // 4800
    float* P      = tapabc + 4800;           // 65536
    float* M      = P + 65536;               // 409600
    float* partial= M + 409600;              // 1024
    float* Wsum   = partial + 1024;          // 204800
    short* wtall  = (short*)(Wsum + 204800); // 124928 shorts
    short* wtA    = wtall;
    short* wtC1   = wtall + 18432;
    short* wtC2   = wtall + 36864;
    short* wtT2   = wtall + 73728;
    unsigned short* tmpb    = (unsigned short*)(wtall + 124928);  // c1out: 16777216
    unsigned short* qfeatb  = tmpb + 16777216;                    // 8388608
    unsigned short* colorsb = qfeatb + 8388608;                   // 16777216

    tapabc_kernel<<<25, 192, 0, stream>>>(pos_w, pos_b, ct1_w, tapabc);
    pfill_kernel<<<64, 1024, 0, stream>>>(tapabc, ct1_b, P);
    prep_ws_kernel<<<1288, 256, 0, stream>>>(ct1_w, a1_w, c1_w, c2_w, ct2_w, Wsum, wtall);
    m_kernel<<<dim3(256, 25), 64, 0, stream>>>(latent, Wsum, M);

    conv5_kernel<<<dim3(256, 4), 256, 0, stream>>>(M, P, wtT2, ct2_b, featb);
    // alpha head: a1 conv + MFMA a2 projection -> s9 -> softmax
    conv3a2_kernel<<<dim3(256, 8), 256, 0, stream>>>(featb, wtA, a1_b, a2_w, s9);
    a2soft_kernel<<<128, 256, 0, stream>>>(s9, a2_b, out);
    // VQ
    vq_mfma_kernel<<<1024, 256, 0, stream>>>(featb, codebook, qfeatb, partial);
    // color head
    conv3_kernel<1><<<dim3(256, 8), 256, 0, stream>>>(qfeatb, wtC1, c1_b, tmpb);
    c2_kernel<<<dim3(256, 4), 256, 0, stream>>>(tmpb, wtC2, c2_b, colorsb);
    recon_kernel<<<dim3(32, 8), 256, 0, stream>>>(colorsb, out);
    loss_kernel<<<1, 256, 0, stream>>>(partial, out);
}